// Round 8
// baseline (1112.224 us; speedup 1.0000x reference)
//
#include <hip/hip_runtime.h>
#include <math.h>

#define NP 256   // datapoints
#define BB 128   // batch
#define DD 784   // dims
#define HS_MIN 1e-7f
#define LOG_HS_MIN -16.11809565095832f   // log(1e-7)
#define LOG_MB -16.811242831518264f      // log(5e-8) — mask bound in log space
#define NEG_HALF_LOG_2PI -0.9189385332046727f
#define NB 49    // 784/16 block-rows of the triangular system
#define BK 4     // batch rows per thread in k_main

// ---------------- ndtri (AS241, double poly) from log_cdf / log_sf ----------------
// Double exp() for the mid branch (d ndtri/dp ~ 8e6 near the mask boundary —
// f32 __expf noise there costs ~0.8 absmax; do NOT "optimize" this).
__device__ double ndtri_logs(float log_cdf_f, float log_sf_f) {
    double lp = (double)log_cdf_f;
    double ls = (double)log_sf_f;
    double p = exp(lp);
    double q = p - 0.5;
    if (fabs(q) <= 0.425) {
        double r = 0.180625 - q * q;
        double num = (((((((2.5090809287301226727e3 * r + 3.3430575583588128105e4) * r
                         + 6.7265770927008700853e4) * r + 4.5921953931549871457e4) * r
                         + 1.3731693765509461125e4) * r + 1.9715909503065514427e3) * r
                         + 1.3314166789178437745e2) * r + 3.3871328727963666080e0);
        double den = (((((((5.2264952788528545610e3 * r + 2.8729085735721942674e4) * r
                         + 3.9307895800092710610e4) * r + 2.1213794301586595867e4) * r
                         + 5.3941960214247511077e3) * r + 6.8718700749205790830e2) * r
                         + 4.2313330701600911252e1) * r + 1.0);
        return q * num / den;
    }
    double r = (q < 0.0) ? sqrt(-lp) : sqrt(-ls);
    double v;
    if (r <= 5.0) {
        r -= 1.6;
        double num = (((((((7.74545014278341407640e-4 * r + 2.27238449892691845833e-2) * r
                         + 2.41780725177450611770e-1) * r + 1.27045825245236838258e0) * r
                         + 3.64784832476320460504e0) * r + 5.76949722146069140550e0) * r
                         + 4.63033784615654529590e0) * r + 1.42343711074968357734e0);
        double den = (((((((1.05075007164441684324e-9 * r + 5.47593808499534494600e-4) * r
                         + 1.51986665636164571966e-2) * r + 1.48103976427480074590e-1) * r
                         + 6.89767334985100004550e-1) * r + 1.67638483018380384940e0) * r
                         + 2.05319162663775882187e0) * r + 1.0);
        v = num / den;
    } else {
        r -= 5.0;
        double num = (((((((2.01033439929228813265e-7 * r + 2.71155556874348757815e-5) * r
                         + 1.24266094738807843860e-3) * r + 2.65321895265761230930e-2) * r
                         + 2.96560571828504891230e-1) * r + 1.78482653991729133580e0) * r
                         + 5.46378491116411436990e0) * r + 6.65790464350110377720e0);
        double den = (((((((2.04426310338993978564e-15 * r + 1.42151175831644588870e-7) * r
                         + 1.84631831751005468180e-5) * r + 7.86869131145613259100e-4) * r
                         + 1.48753612908506148525e-2) * r + 1.36929880922735805310e-1) * r
                         + 5.99832206555887937690e-1) * r + 1.0);
        v = num / den;
    }
    return (q < 0.0) ? -v : v;
}

// ---------------- K0: lsew[d] = logsumexp_n kde_weights[n,d] (block per d) ----------------
__global__ __launch_bounds__(256) void k_lsew(const float* __restrict__ kw,
                                              float* __restrict__ lsew) {
    __shared__ float red[4];
    int d = blockIdx.x;
    int n = threadIdx.x;          // NP == 256 == blockDim
    float a = kw[n * DD + d];
    float m = a;
    #pragma unroll
    for (int off = 32; off; off >>= 1) m = fmaxf(m, __shfl_xor(m, off, 64));
    if ((threadIdx.x & 63) == 0) red[threadIdx.x >> 6] = m;
    __syncthreads();
    m = fmaxf(fmaxf(red[0], red[1]), fmaxf(red[2], red[3]));
    __syncthreads();
    float e = __expf(a - m);
    #pragma unroll
    for (int off = 32; off; off >>= 1) e += __shfl_xor(e, off, 64);
    if ((threadIdx.x & 63) == 0) red[threadIdx.x >> 6] = e;
    __syncthreads();
    if (threadIdx.x == 0)
        lsew[d] = m + __logf(red[0] + red[1] + red[2] + red[3]);
}

// ---------------- K1: per-(n,d) precompute, packed float4 {dp, 1/hs, w, w-lhc} ----------------
__global__ __launch_bounds__(256) void k_prep(const float* __restrict__ kw,
                                              const float* __restrict__ log_hs,
                                              const float* __restrict__ dp,
                                              const float* __restrict__ lsew,
                                              float4* __restrict__ pk) {
    int n = blockIdx.x;
    for (int d = threadIdx.x; d < DD; d += 256) {
        int idx = n * DD + d;
        float lh = log_hs[idx];
        float hs = fmaxf(__expf(lh), HS_MIN);
        float lhc = fmaxf(lh, LOG_HS_MIN);
        float wv = kw[idx] - lsew[d];
        pk[idx] = make_float4(dp[idx], 1.f / hs, wv, wv - lhc);
    }
}

// ---------------- K2: main KDE + inverse + term (BK batch rows / thread) ----------------
__global__ __launch_bounds__(128) void k_main(const float* __restrict__ x,
                                              const float4* __restrict__ pk,
                                              float* __restrict__ Y,
                                              float* __restrict__ T) {
    int g = blockIdx.x * 128 + threadIdx.x;        // g < (BB/BK)*DD exactly
    int d = g % DD;
    int b0 = (g / DD) * BK;
    float xv[BK], m1[BK], s1[BK], m2[BK], s2[BK], m3[BK], s3[BK];
    #pragma unroll
    for (int i = 0; i < BK; ++i) {
        xv[i] = x[(b0 + i) * DD + d];
        m1[i] = -INFINITY; s1[i] = 0.f;
        m2[i] = -INFINITY; s2[i] = 0.f;
        m3[i] = -INFINITY; s3[i] = 0.f;
    }
    for (int n = 0; n < NP; ++n) {
        float4 c = pk[n * DD + d];          // {dp, ihs, w, w-lhc}
        #pragma unroll
        for (int i = 0; i < BK; ++i) {
            float u = (c.x - xv[i]) * c.y;
            float e = __expf(-fabsf(u));
            float l1p = __logf(1.f + e);
            float sp = fmaxf(u, 0.f) + l1p;
            float a1 = c.z - sp;
            float a2 = fminf(u, 0.f) - l1p + c.z;
            float a3 = u - 2.f * sp + c.w;
            float d1 = a1 - m1[i]; float E1 = __expf(-fabsf(d1));
            s1[i] = (d1 <= 0.f) ? (s1[i] + E1) : (s1[i] * E1 + 1.f);
            m1[i] = fmaxf(m1[i], a1);
            float d2 = a2 - m2[i]; float E2 = __expf(-fabsf(d2));
            s2[i] = (d2 <= 0.f) ? (s2[i] + E2) : (s2[i] * E2 + 1.f);
            m2[i] = fmaxf(m2[i], a2);
            float d3 = a3 - m3[i]; float E3 = __expf(-fabsf(d3));
            s3[i] = (d3 <= 0.f) ? (s3[i] + E3) : (s3[i] * E3 + 1.f);
            m3[i] = fmaxf(m3[i], a3);
        }
    }
    #pragma unroll
    for (int i = 0; i < BK; ++i) {
        float log_cdf = m1[i] + __logf(s1[i]);
        float log_sf  = m2[i] + __logf(s2[i]);
        float log_pdf = m3[i] + __logf(s3[i]);
        bool right = (log_sf  <= LOG_MB);
        bool left  = (log_cdf <= LOG_MB);
        float inv, lgd;
        if (right) {
            float t2 = -2.f * log_sf;
            inv = sqrtf(t2);
            lgd = 0.5f * __logf(t2) - log_sf;
        } else if (left) {
            float t2 = -2.f * log_cdf;
            inv = -sqrtf(t2);
            lgd = 0.5f * __logf(t2) - log_cdf;
        } else {
            inv = (float)ndtri_logs(log_cdf, log_sf);
            lgd = -0.5f * inv * inv + NEG_HALF_LOG_2PI;
        }
        Y[(b0 + i) * DD + d] = inv;
        T[(b0 + i) * DD + d] = log_pdf - lgd;
    }
}

// ---------------- K3: log_det reduction ----------------
__global__ __launch_bounds__(256) void k_logdet(const float* __restrict__ T,
                                                const float* __restrict__ ld_in,
                                                float* __restrict__ out) {
    __shared__ float red[4];
    int b = blockIdx.x;
    float s = 0.f;
    for (int d = threadIdx.x; d < DD; d += 256) s += T[b * DD + d];
    #pragma unroll
    for (int off = 32; off; off >>= 1) s += __shfl_down(s, off, 64);
    if ((threadIdx.x & 63) == 0) red[threadIdx.x >> 6] = s;
    __syncthreads();
    if (threadIdx.x == 0) out[BB * DD + b] = ld_in[b] + red[0] + red[1] + red[2] + red[3];
}

// ---------------- K4: normalize reflector rows ----------------
__global__ __launch_bounds__(256) void k_vn(const float* __restrict__ vs,
                                            float* __restrict__ vn) {
    __shared__ float red[4];
    int i = blockIdx.x;
    float ss = 0.f;
    for (int j = threadIdx.x; j < DD; j += 256) {
        float v = vs[i * DD + j];
        ss += v * v;
    }
    #pragma unroll
    for (int off = 32; off; off >>= 1) ss += __shfl_down(ss, off, 64);
    if ((threadIdx.x & 63) == 0) red[threadIdx.x >> 6] = ss;
    __syncthreads();
    float inorm = rsqrtf(red[0] + red[1] + red[2] + red[3]);
    for (int j = threadIdx.x; j < DD; j += 256)
        vn[i * DD + j] = vs[i * DD + j] * inorm;
}

// ---------------- K5: full Gram G = VN VN^T (784x784), 64x64 fp32 tiles ----------------
__global__ __launch_bounds__(256) void k_gram_full(const float* __restrict__ A,
                                                   float* __restrict__ G) {
    __shared__ float As[64][20];
    __shared__ float Bs[64][20];
    int t = threadIdx.x;
    int bi = blockIdx.y * 64, bj = blockIdx.x * 64;
    int lr = t >> 2, lc = (t & 3) * 4;
    int ari = min(bi + lr, DD - 1);
    int brj = min(bj + lr, DD - 1);
    int tx = t & 15, ty = t >> 4;
    float c[4][4] = {};
    for (int k0 = 0; k0 < DD; k0 += 16) {
        *(float4*)(&As[lr][lc]) = *(const float4*)(A + ari * DD + k0 + lc);
        *(float4*)(&Bs[lr][lc]) = *(const float4*)(A + brj * DD + k0 + lc);
        __syncthreads();
        #pragma unroll
        for (int kk = 0; kk < 16; ++kk) {
            float a[4], b[4];
            #pragma unroll
            for (int i = 0; i < 4; ++i) a[i] = As[ty * 4 + i][kk];
            #pragma unroll
            for (int j = 0; j < 4; ++j) b[j] = Bs[tx * 4 + j][kk];
            #pragma unroll
            for (int i = 0; i < 4; ++i)
                #pragma unroll
                for (int j = 0; j < 4; ++j)
                    c[i][j] += a[i] * b[j];
        }
        __syncthreads();
    }
    #pragma unroll
    for (int i = 0; i < 4; ++i) {
        int r = bi + ty * 4 + i;
        if (r >= DD) break;
        #pragma unroll
        for (int j = 0; j < 4; ++j) {
            int cc = bj + tx * 4 + j;
            if (cc < DD) G[r * DD + cc] = c[i][j];
        }
    }
}

// ---------------- K6: invert the 49 diagonal 16x16 unit-lower blocks of L ----------------
// L[r][k] = 2*G[r][k] (k<r), unit diagonal. Dinv[i] = (L_ii)^-1, row-major 16x16.
__global__ __launch_bounds__(64) void k_dinv(const float* __restrict__ G,
                                             float* __restrict__ Dinv) {
    int i = blockIdx.x, cth = threadIdx.x;
    if (cth >= 16) return;
    float x[16];
    #pragma unroll
    for (int r = 0; r < 16; ++r) x[r] = (r == cth) ? 1.f : 0.f;
    for (int r = cth + 1; r < 16; ++r) {
        float a = 0.f;
        for (int k = cth; k < r; ++k)
            a -= 2.f * G[(i * 16 + r) * DD + i * 16 + k] * x[k];
        x[r] = a;
    }
    for (int r = 0; r < 16; ++r) Dinv[i * 256 + r * 16 + cth] = x[r];
}

// ---------------- K7: P = VN * Y^T  (784 x 128) ----------------
__global__ __launch_bounds__(256) void k_p(const float* __restrict__ VN,
                                           const float* __restrict__ Y,
                                           float* __restrict__ P) {
    __shared__ float Vs[64][20];
    __shared__ float Ys[32][20];
    int t = threadIdx.x;
    int k0 = blockIdx.x * 64, b0 = blockIdx.y * 32;
    int lr = t >> 2, lc = (t & 3) * 4;
    int vri = min(k0 + lr, DD - 1);
    int tx = t & 15, ty = t >> 4;
    float c[4][2] = {};
    for (int d0 = 0; d0 < DD; d0 += 16) {
        *(float4*)(&Vs[lr][lc]) = *(const float4*)(VN + vri * DD + d0 + lc);
        if (t < 128)
            *(float4*)(&Ys[lr][lc]) = *(const float4*)(Y + (b0 + lr) * DD + d0 + lc);
        __syncthreads();
        #pragma unroll
        for (int kk = 0; kk < 16; ++kk) {
            float a[4], b[2];
            #pragma unroll
            for (int i = 0; i < 4; ++i) a[i] = Vs[ty * 4 + i][kk];
            #pragma unroll
            for (int j = 0; j < 2; ++j) b[j] = Ys[tx * 2 + j][kk];
            #pragma unroll
            for (int i = 0; i < 4; ++i)
                #pragma unroll
                for (int j = 0; j < 2; ++j)
                    c[i][j] += a[i] * b[j];
        }
        __syncthreads();
    }
    #pragma unroll
    for (int i = 0; i < 4; ++i) {
        int r = k0 + ty * 4 + i;
        if (r >= DD) break;
        #pragma unroll
        for (int j = 0; j < 2; ++j)
            P[r * BB + b0 + tx * 2 + j] = c[i][j];
    }
}

// ---------------- K8: blocked forward substitution  L S = 2P ----------------
// 8 independent blocks, each owns 16 batch columns. Sequential over 49 block-rows
// INSIDE the workgroup (no grid sync). thread (r = t&15, c = t>>4); S kept in LDS
// transposed [c][k] (pad 788) for contiguous float4 k-runs.
__global__ __launch_bounds__(256) void k_solve(const float* __restrict__ P,
                                               const float* __restrict__ G,
                                               const float* __restrict__ Dinv,
                                               float* __restrict__ S) {
    __shared__ float Sl[16][788];
    __shared__ float ql[16][17];
    int t = threadIdx.x;
    int r = t & 15, c = t >> 4;
    int c0 = blockIdx.x * 16;
    for (int i = 0; i < NB; ++i) {
        int row = i * 16 + r;
        float acc = 2.f * P[row * BB + c0 + c];
        const float* Lrow = G + row * DD;       // L[row][k] = 2*G[row][k], k < 16i
        int K = i * 16;
        for (int k = 0; k < K; k += 4) {
            float4 lv = *(const float4*)(Lrow + k);
            float4 sv = *(const float4*)(&Sl[c][k]);
            acc -= 2.f * (lv.x * sv.x + lv.y * sv.y + lv.z * sv.z + lv.w * sv.w);
        }
        ql[r][c] = acc;
        __syncthreads();
        float s = 0.f;
        const float* Di = Dinv + i * 256 + r * 16;
        #pragma unroll
        for (int k = 0; k < 16; ++k) s += Di[k] * ql[k][c];
        Sl[c][row] = s;
        __syncthreads();
    }
    for (int idx = t; idx < 16 * DD; idx += 256) {
        int cc = idx / DD, k = idx - cc * DD;
        S[(c0 + cc) * DD + k] = Sl[cc][k];
    }
}

// ---------------- K9: X_out = Y - S^T-applied:  out[b][d] = Y[b][d] - sum_k S[b][k] VN[k][d] ----------------
__global__ __launch_bounds__(256) void k_apply(const float* __restrict__ Y,
                                               const float* __restrict__ S,
                                               const float* __restrict__ VN,
                                               float* __restrict__ out) {
    __shared__ float Ss[32][20];
    __shared__ float Vs[16][68];
    int t = threadIdx.x;
    int b0 = blockIdx.x * 32, d0 = blockIdx.y * 64;
    int tx = t & 15, ty = t >> 4;
    float c[2][4] = {};
    for (int k0 = 0; k0 < DD; k0 += 16) {
        if (t < 128) {
            int lr = t >> 2, lc = (t & 3) * 4;
            *(float4*)(&Ss[lr][lc]) = *(const float4*)(S + (b0 + lr) * DD + k0 + lc);
        }
        {
            int kr = t >> 4, dc = (t & 15) * 4;
            // d0+dc can run past row end for the last d-tile; lands in the S
            // buffer (allocated, unused values) — stores are guarded below.
            *(float4*)(&Vs[kr][dc]) = *(const float4*)(VN + (k0 + kr) * DD + d0 + dc);
        }
        __syncthreads();
        #pragma unroll
        for (int kk = 0; kk < 16; ++kk) {
            float sv[2], vv[4];
            #pragma unroll
            for (int i = 0; i < 2; ++i) sv[i] = Ss[ty * 2 + i][kk];
            #pragma unroll
            for (int j = 0; j < 4; ++j) vv[j] = Vs[kk][tx * 4 + j];
            #pragma unroll
            for (int i = 0; i < 2; ++i)
                #pragma unroll
                for (int j = 0; j < 4; ++j)
                    c[i][j] += sv[i] * vv[j];
        }
        __syncthreads();
    }
    #pragma unroll
    for (int i = 0; i < 2; ++i) {
        int b = b0 + ty * 2 + i;
        #pragma unroll
        for (int j = 0; j < 4; ++j) {
            int d = d0 + tx * 4 + j;
            if (d < DD) out[b * DD + d] = Y[b * DD + d] - c[i][j];
        }
    }
}

// ---------------- launch ----------------
extern "C" void kernel_launch(void* const* d_in, const int* in_sizes, int n_in,
                              void* d_out, int out_size, void* d_ws, size_t ws_size,
                              hipStream_t stream) {
    const float* x      = (const float*)d_in[0];   // [B,D]
    const float* ld_in  = (const float*)d_in[1];   // [B]
    const float* dp     = (const float*)d_in[2];   // [N,D]
    const float* log_hs = (const float*)d_in[3];   // [N,D]
    const float* kw     = (const float*)d_in[4];   // [N,D]
    const float* vs     = (const float*)d_in[5];   // [D,D]
    float* out = (float*)d_out;                    // x_out [B,D] then log_det [B]

    float* ws   = (float*)d_ws;
    float* lsew = ws;                               // 1024
    float4* pk  = (float4*)(ws + 1024);             // N*D float4 = 802816 floats
    float* G    = ws + 1024;                        // ALIAS of pk: G (614656) written
                                                    // by k_gram_full AFTER k_main is done
    float* Y    = ws + 1024 + NP * DD * 4;          // B*D = 100352
    float* T    = Y + BB * DD;                      // B*D = 100352
    float* P    = T;                                // ALIAS of T: written after k_logdet
    float* VN   = T + BB * DD;                      // D*D = 614656
    float* S    = VN + DD * DD;                     // B*D = 100352
    float* Dinv = S + BB * DD;                      // 49*256 = 12544
    // total ~6.93 MB (<= round-6's proven 6.53 MB + ~0.4)

    k_lsew<<<DD, 256, 0, stream>>>(kw, lsew);
    k_prep<<<NP, 256, 0, stream>>>(kw, log_hs, dp, lsew, pk);
    k_main<<<(BB / BK) * DD / 128, 128, 0, stream>>>(x, pk, Y, T);
    k_logdet<<<BB, 256, 0, stream>>>(T, ld_in, out);
    k_vn<<<DD, 256, 0, stream>>>(vs, VN);
    k_gram_full<<<dim3(13, 13), 256, 0, stream>>>(VN, G);
    k_dinv<<<NB, 64, 0, stream>>>(G, Dinv);
    k_p<<<dim3(13, 4), 256, 0, stream>>>(VN, Y, P);
    k_solve<<<BB / 16, 256, 0, stream>>>(P, G, Dinv, S);
    k_apply<<<dim3(4, 13), 256, 0, stream>>>(Y, S, VN, out);
}